// Round 1
// baseline (313.263 us; speedup 1.0000x reference)
//
#include <hip/hip_runtime.h>
#include <hip/hip_bf16.h>

typedef __attribute__((ext_vector_type(8))) short bf16x8;
typedef __attribute__((ext_vector_type(4))) float f32x4;

#define C_    1024
#define MROWS 32768   // B*T*QH
#define D_    256     // per-head dim = K1 = N
#define S_TOT 4096
#define SCH   64      // S-chunk
#define NWAVE 4

__device__ __forceinline__ unsigned short f2bf(float f) {
  union { float f; unsigned int u; } v; v.f = f;
  unsigned int u = v.u;
  u += 0x7fffu + ((u >> 16) & 1u);   // round-to-nearest-even
  return (unsigned short)(u >> 16);
}

// ---------------- LayerNorm -> bf16 ----------------
__global__ __launch_bounds__(256) void ln_kernel(const float* __restrict__ res,
                                                 const float* __restrict__ g,
                                                 const float* __restrict__ b,
                                                 unsigned short* __restrict__ xq) {
  int row = blockIdx.x;
  int tid = threadIdx.x;
  const float* r = res + (size_t)row * C_;
  float4 x = *(const float4*)(r + tid * 4);
  float s  = x.x + x.y + x.z + x.w;
  float s2 = x.x * x.x + x.y * x.y + x.z * x.z + x.w * x.w;
  #pragma unroll
  for (int off = 32; off > 0; off >>= 1) {
    s  += __shfl_down(s, off, 64);
    s2 += __shfl_down(s2, off, 64);
  }
  __shared__ float ws[NWAVE], ws2[NWAVE];
  int wave = tid >> 6, lane = tid & 63;
  if (lane == 0) { ws[wave] = s; ws2[wave] = s2; }
  __syncthreads();
  float ts  = ws[0] + ws[1] + ws[2] + ws[3];
  float ts2 = ws2[0] + ws2[1] + ws2[2] + ws2[3];
  float mu  = ts * (1.0f / C_);
  float var = ts2 * (1.0f / C_) - mu * mu;
  float rs  = rsqrtf(var + 1e-5f);
  int c = tid * 4;
  float4 gg = *(const float4*)(g + c);
  float4 bb = *(const float4*)(b + c);
  unsigned short o[4];
  o[0] = f2bf((x.x - mu) * rs * gg.x + bb.x);
  o[1] = f2bf((x.y - mu) * rs * gg.y + bb.y);
  o[2] = f2bf((x.z - mu) * rs * gg.z + bb.z);
  o[3] = f2bf((x.w - mu) * rs * gg.w + bb.w);
  *(ushort4*)(xq + (size_t)row * C_ + c) = *(ushort4*)o;
}

// ---------------- K cast: w_fc flat -> bf16 ----------------
__global__ __launch_bounds__(256) void prep_k(const float* __restrict__ wfc,
                                              unsigned short* __restrict__ kq) {
  int i = (blockIdx.x * 256 + threadIdx.x) * 4;
  float4 x = *(const float4*)(wfc + i);
  unsigned short o[4] = { f2bf(x.x), f2bf(x.y), f2bf(x.z), f2bf(x.w) };
  *(ushort4*)(kq + i) = *(ushort4*)o;
}

// ---------------- V transpose: vt_blk[sc][d][s'] = v[s][d] ----------------
// v[s][d] = w_proj[(s%4)*256 + d][s//4]
__global__ __launch_bounds__(256) void prep_v(const float* __restrict__ wproj,
                                              unsigned short* __restrict__ vq) {
  int o  = blockIdx.x * 256 + threadIdx.x;   // 0 .. 1M-1
  int sp = o & 63;
  int d  = (o >> 6) & 255;
  int sc = o >> 14;
  int s  = sc * 64 + sp;
  float v = wproj[(size_t)((s & 3) * 256 + d) * 1024 + (s >> 2)];
  vq[o] = f2bf(v);
}

// ---------------- fused relu^2 "attention" main ----------------
__global__ __launch_bounds__(256, 2) void mlpmha_main(
    const unsigned short* __restrict__ xq,
    const unsigned short* __restrict__ kq,
    const unsigned short* __restrict__ vq,
    const float* __restrict__ res,
    float* __restrict__ out) {
  // padded (+8 bf16 = 16B) -> row stride stays 16B-aligned, 2-way bank alias only
  __shared__ unsigned short ldsK[SCH][D_ + 8];          // 64 x 264 : K rows (s' x d)
  __shared__ unsigned short ldsV[D_][SCH + 8];          // 256 x 72 : V^T     (d x s')
  __shared__ unsigned short ldsP[NWAVE][16][SCH + 8];   // per-wave P transpose buffer

  int tid  = threadIdx.x;
  int wave = tid >> 6;
  int lane = tid & 63;
  int l16  = lane & 15;
  int quad = lane >> 4;
  int wgM  = blockIdx.x * 64;

  // Q fragments: A-layout, 16 rows/wave, K1=256 -> 8 chunks of 32
  bf16x8 qf[8];
  {
    const unsigned short* qrow =
        xq + (size_t)(wgM + wave * 16 + l16) * D_ + quad * 8;
    #pragma unroll
    for (int kc = 0; kc < 8; ++kc)
      qf[kc] = *(const bf16x8*)(qrow + kc * 32);
  }

  f32x4 acc[16];
  #pragma unroll
  for (int i = 0; i < 16; ++i) acc[i] = (f32x4){0.f, 0.f, 0.f, 0.f};

  for (int sc = 0; sc < S_TOT / SCH; ++sc) {
    __syncthreads();
    // ---- stage K-tile (64x256 bf16, contiguous 32KB) and V^T-tile (contiguous 32KB)
    {
      const uint4* srck = (const uint4*)(kq + (size_t)sc * SCH * D_);
      #pragma unroll
      for (int it = 0; it < 8; ++it) {
        int c = it * 256 + tid;
        *(uint4*)&ldsK[c >> 5][(c & 31) * 8] = srck[c];
      }
      const uint4* srcv = (const uint4*)(vq + (size_t)sc * D_ * SCH);
      #pragma unroll
      for (int it = 0; it < 8; ++it) {
        int c = it * 256 + tid;
        *(uint4*)&ldsV[c >> 3][(c & 7) * 8] = srcv[c];
      }
    }
    __syncthreads();

    // ---- scores: 16 tokens x 64 s  (4 n-tiles, K=256 in 8 MFMA steps)
    f32x4 sacc[4];
    #pragma unroll
    for (int i = 0; i < 4; ++i) sacc[i] = (f32x4){0.f, 0.f, 0.f, 0.f};
    #pragma unroll
    for (int kc = 0; kc < 8; ++kc) {
      #pragma unroll
      for (int sn = 0; sn < 4; ++sn) {
        bf16x8 kb = *(const bf16x8*)&ldsK[sn * 16 + l16][kc * 32 + quad * 8];
        sacc[sn] = __builtin_amdgcn_mfma_f32_16x16x32_bf16(qf[kc], kb, sacc[sn], 0, 0, 0);
      }
    }

    // ---- p = relu(score)^2, C-layout -> bf16 -> LDS (per-wave, for A-layout reload)
    #pragma unroll
    for (int sn = 0; sn < 4; ++sn) {
      #pragma unroll
      for (int r = 0; r < 4; ++r) {
        float v = sacc[sn][r];
        v = v > 0.f ? v * v : 0.f;
        ldsP[wave][quad * 4 + r][sn * 16 + l16] = f2bf(v);
      }
    }

    // ---- PV: K-dim = s' (2 chunks of 32), N = 256 (16 n-tiles)
    #pragma unroll
    for (int kc2 = 0; kc2 < 2; ++kc2) {
      bf16x8 pa = *(const bf16x8*)&ldsP[wave][l16][kc2 * 32 + quad * 8];
      #pragma unroll
      for (int dn = 0; dn < 16; ++dn) {
        bf16x8 vb = *(const bf16x8*)&ldsV[dn * 16 + l16][kc2 * 32 + quad * 8];
        acc[dn] = __builtin_amdgcn_mfma_f32_16x16x32_bf16(pa, vb, acc[dn], 0, 0, 0);
      }
    }
  }

  // ---- epilogue: out = residual + acc  (C/D layout: row=quad*4+r, col=dn*16+l16)
  #pragma unroll
  for (int r = 0; r < 4; ++r) {
    size_t row = (size_t)(wgM + wave * 16 + quad * 4 + r) * D_;
    #pragma unroll
    for (int dn = 0; dn < 16; ++dn) {
      size_t idx = row + dn * 16 + l16;
      out[idx] = res[idx] + acc[dn][r];
    }
  }
}

extern "C" void kernel_launch(void* const* d_in, const int* in_sizes, int n_in,
                              void* d_out, int out_size, void* d_ws, size_t ws_size,
                              hipStream_t stream) {
  const float* res   = (const float*)d_in[0];
  const float* wfc   = (const float*)d_in[1];
  const float* wproj = (const float*)d_in[2];
  const float* g     = (const float*)d_in[3];
  const float* b     = (const float*)d_in[4];
  float* out = (float*)d_out;

  unsigned short* xq = (unsigned short*)d_ws;              // 8192*1024 bf16 = 16 MB
  unsigned short* kq = xq + (size_t)8192 * 1024;           // 4096*256  bf16 =  2 MB
  unsigned short* vq = kq + (size_t)4096 * 256;            // 4096*256  bf16 =  2 MB

  ln_kernel<<<8192, 256, 0, stream>>>(res, g, b, xq);
  prep_k<<<1024, 256, 0, stream>>>(wfc, kq);
  prep_v<<<4096, 256, 0, stream>>>(wproj, vq);
  mlpmha_main<<<512, 256, 0, stream>>>(xq, kq, vq, res, out);
}

// Round 2
// 299.365 us; speedup vs baseline: 1.0464x; 1.0464x over previous
//
#include <hip/hip_runtime.h>
#include <hip/hip_bf16.h>

typedef __attribute__((ext_vector_type(8))) short bf16x8;
typedef __attribute__((ext_vector_type(4))) float f32x4;
typedef unsigned short ushort_t;

#define C_    1024
#define MROWS 32768   // B*T*QH
#define D_    256     // per-head dim
#define S_TOT 4096
#define SCH   32      // S-chunk
#define NCH   (S_TOT / SCH)   // 128 chunks

__device__ __forceinline__ unsigned short f2bf(float f) {
  union { float f; unsigned int u; } v; v.f = f;
  unsigned int u = v.u;
  u += 0x7fffu + ((u >> 16) & 1u);   // round-to-nearest-even
  return (unsigned short)(u >> 16);
}

__device__ __forceinline__ void async16(const void* g, void* l) {
  __builtin_amdgcn_global_load_lds(
      (const __attribute__((address_space(1))) unsigned int*)g,
      (__attribute__((address_space(3))) unsigned int*)l, 16, 0, 0);
}

// ---------------- LayerNorm -> bf16 ----------------
__global__ __launch_bounds__(256) void ln_kernel(const float* __restrict__ res,
                                                 const float* __restrict__ g,
                                                 const float* __restrict__ b,
                                                 unsigned short* __restrict__ xq) {
  int row = blockIdx.x;
  int tid = threadIdx.x;
  const float* r = res + (size_t)row * C_;
  float4 x = *(const float4*)(r + tid * 4);
  float s  = x.x + x.y + x.z + x.w;
  float s2 = x.x * x.x + x.y * x.y + x.z * x.z + x.w * x.w;
  #pragma unroll
  for (int off = 32; off > 0; off >>= 1) {
    s  += __shfl_down(s, off, 64);
    s2 += __shfl_down(s2, off, 64);
  }
  __shared__ float ws[4], ws2[4];
  int wave = tid >> 6, lane = tid & 63;
  if (lane == 0) { ws[wave] = s; ws2[wave] = s2; }
  __syncthreads();
  float ts  = ws[0] + ws[1] + ws[2] + ws[3];
  float ts2 = ws2[0] + ws2[1] + ws2[2] + ws2[3];
  float mu  = ts * (1.0f / C_);
  float var = ts2 * (1.0f / C_) - mu * mu;
  float rs  = rsqrtf(var + 1e-5f);
  int c = tid * 4;
  float4 gg = *(const float4*)(g + c);
  float4 bb = *(const float4*)(b + c);
  unsigned short o[4];
  o[0] = f2bf((x.x - mu) * rs * gg.x + bb.x);
  o[1] = f2bf((x.y - mu) * rs * gg.y + bb.y);
  o[2] = f2bf((x.z - mu) * rs * gg.z + bb.z);
  o[3] = f2bf((x.w - mu) * rs * gg.w + bb.w);
  *(ushort4*)(xq + (size_t)row * C_ + c) = *(ushort4*)o;
}

// ---------------- K -> bf16, pre-swizzled into MFMA B-fragment order --------
// kq[((sc2*8+kc)*2+sn)*64+lane][j] = K[s][d],
//   s = sc2*32 + sn*16 + (lane&15), d = kc*32 + (lane>>4)*8 + j
__global__ __launch_bounds__(256) void prep_k(const float* __restrict__ wfc,
                                              unsigned short* __restrict__ kq) {
  int t = blockIdx.x * 256 + threadIdx.x;   // 131072 frag-rows of 8
  int lane = t & 63;
  int sn  = (t >> 6) & 1;
  int kc  = (t >> 7) & 7;
  int sc2 = t >> 10;
  int s = sc2 * 32 + sn * 16 + (lane & 15);
  int d = kc * 32 + (lane >> 4) * 8;
  const float* src = wfc + (size_t)s * D_ + d;
  float4 a = *(const float4*)src;
  float4 b = *(const float4*)(src + 4);
  unsigned short o[8] = { f2bf(a.x), f2bf(a.y), f2bf(a.z), f2bf(a.w),
                          f2bf(b.x), f2bf(b.y), f2bf(b.z), f2bf(b.w) };
  *(uint4*)(kq + (size_t)t * 8) = *(uint4*)o;
}

// ---------------- V -> bf16, pre-swizzled into MFMA B-fragment order --------
// vq[((sc2*16+dn)*64+lane)*8+j] = V[s][d],
//   s = sc2*32 + (lane>>4)*8 + j, d = dn*16 + (lane&15)
//   V[s][d] = w_proj[(s&3)*256 + d][s>>2]
__global__ __launch_bounds__(256) void prep_v(const float* __restrict__ wproj,
                                              unsigned short* __restrict__ vq) {
  __shared__ unsigned short tile[8192];   // [p=(s&3)*256+d][c=(s_local>>2)] : 1024 x 8
  int b = blockIdx.x;                      // sc2 : s in [b*32, b*32+32)
  int tid = threadIdx.x;
  int c0 = b * 8;
  #pragma unroll
  for (int it = 0; it < 4; ++it) {
    int row = it * 256 + tid;              // 0..1023 rows of w_proj
    const float* src = wproj + (size_t)row * C_ + c0;
    float4 a = *(const float4*)src;
    float4 bb = *(const float4*)(src + 4);
    unsigned short* dst = &tile[row * 8];
    dst[0] = f2bf(a.x);  dst[1] = f2bf(a.y);  dst[2] = f2bf(a.z);  dst[3] = f2bf(a.w);
    dst[4] = f2bf(bb.x); dst[5] = f2bf(bb.y); dst[6] = f2bf(bb.z); dst[7] = f2bf(bb.w);
  }
  __syncthreads();
  #pragma unroll
  for (int it = 0; it < 4; ++it) {
    int slot = it * 256 + tid;             // 0..1023 = dn*64 + lane
    int lane = slot & 63;
    int dn   = slot >> 6;
    int d = dn * 16 + (lane & 15);
    int sl0 = (lane >> 4) * 8;
    unsigned short o[8];
    #pragma unroll
    for (int j = 0; j < 8; ++j) {
      int sl = sl0 + j;
      o[j] = tile[((sl & 3) * 256 + d) * 8 + (sl >> 2)];
    }
    *(uint4*)(vq + (size_t)b * 8192 + (size_t)slot * 8) = *(uint4*)o;
  }
}

// ---------------- fused main: WG=128 rows, scores M-split, PV N-split -------
__global__ __launch_bounds__(256, 1) void mlpmha_main(
    const unsigned short* __restrict__ xq,
    const unsigned short* __restrict__ kq,
    const unsigned short* __restrict__ vq,
    const float* __restrict__ res,
    float* __restrict__ out) {
  __shared__ unsigned short ldsK[2][8192];   // 16KB x2, fragment-linear
  __shared__ unsigned short ldsV[8192];      // 16KB, fragment-linear
  __shared__ unsigned short ldsP[128][36];   // +4 pad: conflict-free wr, b64 rd

  int tid  = threadIdx.x;
  int wave = tid >> 6;
  int lane = tid & 63;
  int l16  = lane & 15;
  int quad = lane >> 4;
  int wgM  = blockIdx.x * 128;
  int wrow = wgM + wave * 32;

  // Q fragments: 2 m-tiles x 8 k-chunks, register resident
  bf16x8 qf[2][8];
  #pragma unroll
  for (int mt = 0; mt < 2; ++mt) {
    const unsigned short* qr = xq + (size_t)(wrow + mt * 16 + l16) * D_ + quad * 8;
    #pragma unroll
    for (int kc = 0; kc < 8; ++kc) qf[mt][kc] = *(const bf16x8*)(qr + kc * 32);
  }

  f32x4 acc[8][4];   // [mt of 128 rows][dn local] -> N cols wave*64 + dnl*16 + l16
  #pragma unroll
  for (int i = 0; i < 8; ++i)
    #pragma unroll
    for (int j = 0; j < 4; ++j) acc[i][j] = (f32x4){0.f, 0.f, 0.f, 0.f};

  int soff = wave * 2048 + lane * 8;   // staging share (shorts)

  // prologue: K chunk 0 -> buf 0
  {
    const unsigned short* kg = kq + soff;
    #pragma unroll
    for (int i = 0; i < 4; ++i)
      async16(kg + i * 512, &ldsK[0][soff + i * 512]);
  }
  __syncthreads();

  for (int sc = 0; sc < NCH; ++sc) {
    int cur = sc & 1;

    // prefetch V(sc) during scores
    {
      const unsigned short* vg = vq + (size_t)sc * 8192 + soff;
      #pragma unroll
      for (int i = 0; i < 4; ++i)
        async16(vg + i * 512, &ldsV[soff + i * 512]);
    }

    // ---- scores: 32 rows/wave x 32 s, K=256
    f32x4 sacc[2][2];
    #pragma unroll
    for (int mt = 0; mt < 2; ++mt)
      #pragma unroll
      for (int sn = 0; sn < 2; ++sn) sacc[mt][sn] = (f32x4){0.f, 0.f, 0.f, 0.f};
    #pragma unroll
    for (int kc = 0; kc < 8; ++kc) {
      #pragma unroll
      for (int sn = 0; sn < 2; ++sn) {
        bf16x8 kb = *(const bf16x8*)&ldsK[cur][(kc * 2 + sn) * 512 + lane * 8];
        #pragma unroll
        for (int mt = 0; mt < 2; ++mt)
          sacc[mt][sn] = __builtin_amdgcn_mfma_f32_16x16x32_bf16(qf[mt][kc], kb, sacc[mt][sn], 0, 0, 0);
      }
    }

    // ---- P = relu(score)^2 -> shared LDS (C-layout rows: quad*4+r)
    #pragma unroll
    for (int mt = 0; mt < 2; ++mt)
      #pragma unroll
      for (int sn = 0; sn < 2; ++sn)
        #pragma unroll
        for (int r = 0; r < 4; ++r) {
          float v = sacc[mt][sn][r];
          v = v > 0.f ? v * v : 0.f;
          ldsP[wave * 32 + mt * 16 + quad * 4 + r][sn * 16 + l16] = f2bf(v);
        }

    __syncthreads();   // P visible to all waves; V(sc) staged (drained here)

    // prefetch K(sc+1) during PV
    if (sc + 1 < NCH) {
      const unsigned short* kg = kq + (size_t)(sc + 1) * 8192 + soff;
      #pragma unroll
      for (int i = 0; i < 4; ++i)
        async16(kg + i * 512, &ldsK[1 - cur][soff + i * 512]);
    }

    // ---- PV: all 128 rows x this wave's 64-col N slice, K = 32
    {
      bf16x8 vb[4];
      #pragma unroll
      for (int dnl = 0; dnl < 4; ++dnl)
        vb[dnl] = *(const bf16x8*)&ldsV[((wave * 4 + dnl) * 64 + lane) * 8];
      #pragma unroll
      for (int mt = 0; mt < 8; ++mt) {
        const unsigned short* pp = &ldsP[mt * 16 + l16][quad * 8];
        union { ushort4 h[2]; bf16x8 v; } pu;
        pu.h[0] = *(const ushort4*)pp;
        pu.h[1] = *(const ushort4*)(pp + 4);
        bf16x8 pa = pu.v;
        #pragma unroll
        for (int dnl = 0; dnl < 4; ++dnl)
          acc[mt][dnl] = __builtin_amdgcn_mfma_f32_16x16x32_bf16(pa, vb[dnl], acc[mt][dnl], 0, 0, 0);
      }
    }

    __syncthreads();   // P/V reusable; K(sc+1) drained
  }

  // ---- epilogue: out = residual + acc
  #pragma unroll
  for (int mt = 0; mt < 8; ++mt)
    #pragma unroll
    for (int r = 0; r < 4; ++r) {
      size_t row = (size_t)(wgM + mt * 16 + quad * 4 + r) * D_;
      #pragma unroll
      for (int dnl = 0; dnl < 4; ++dnl) {
        size_t idx = row + wave * 64 + dnl * 16 + l16;
        out[idx] = res[idx] + acc[mt][dnl][r];
      }
    }
}

extern "C" void kernel_launch(void* const* d_in, const int* in_sizes, int n_in,
                              void* d_out, int out_size, void* d_ws, size_t ws_size,
                              hipStream_t stream) {
  const float* res   = (const float*)d_in[0];
  const float* wfc   = (const float*)d_in[1];
  const float* wproj = (const float*)d_in[2];
  const float* g     = (const float*)d_in[3];
  const float* b     = (const float*)d_in[4];
  float* out = (float*)d_out;

  unsigned short* xq = (unsigned short*)d_ws;              // 32768*256 bf16 = 16 MB
  unsigned short* kq = xq + (size_t)MROWS * D_;            // 4096*256 bf16  =  2 MB
  unsigned short* vq = kq + (size_t)S_TOT * D_;            // 4096*256 bf16  =  2 MB

  ln_kernel<<<8192, 256, 0, stream>>>(res, g, b, xq);
  prep_k<<<512, 256, 0, stream>>>(wfc, kq);
  prep_v<<<128, 256, 0, stream>>>(wproj, vq);
  mlpmha_main<<<256, 256, 0, stream>>>(xq, kq, vq, res, out);
}

// Round 3
// 242.680 us; speedup vs baseline: 1.2908x; 1.2336x over previous
//
#include <hip/hip_runtime.h>
#include <hip/hip_bf16.h>

typedef __attribute__((ext_vector_type(8))) short bf16x8;
typedef __attribute__((ext_vector_type(4))) float f32x4;

#define C_    1024
#define MROWS 32768   // B*T*QH
#define D_    256     // per-head dim
#define S_TOT 4096
#define SCH   32      // S-chunk
#define NCH   (S_TOT / SCH)   // 128 chunks

__device__ __forceinline__ unsigned short f2bf(float f) {
  union { float f; unsigned int u; } v; v.f = f;
  unsigned int u = v.u;
  u += 0x7fffu + ((u >> 16) & 1u);   // round-to-nearest-even
  return (unsigned short)(u >> 16);
}

__device__ __forceinline__ void async16(const void* g, void* l) {
  __builtin_amdgcn_global_load_lds(
      (const __attribute__((address_space(1))) unsigned int*)g,
      (__attribute__((address_space(3))) unsigned int*)l, 16, 0, 0);
}

// ---------------- LayerNorm -> bf16 (one wave per row) ----------------
__global__ __launch_bounds__(256) void ln_kernel(const float* __restrict__ res,
                                                 const float* __restrict__ g,
                                                 const float* __restrict__ b,
                                                 unsigned short* __restrict__ xq) {
  int wave = threadIdx.x >> 6, lane = threadIdx.x & 63;
  int row = blockIdx.x * 4 + wave;
  const float* r = res + (size_t)row * C_;
  float4 x[4];
  float s = 0.f, s2 = 0.f;
  #pragma unroll
  for (int i = 0; i < 4; ++i) {
    x[i] = *(const float4*)(r + i * 256 + lane * 4);
    s  += x[i].x + x[i].y + x[i].z + x[i].w;
    s2 += x[i].x * x[i].x + x[i].y * x[i].y + x[i].z * x[i].z + x[i].w * x[i].w;
  }
  #pragma unroll
  for (int off = 32; off > 0; off >>= 1) {
    s  += __shfl_xor(s, off, 64);
    s2 += __shfl_xor(s2, off, 64);
  }
  float mu  = s * (1.0f / C_);
  float var = s2 * (1.0f / C_) - mu * mu;
  float rs  = rsqrtf(var + 1e-5f);
  #pragma unroll
  for (int i = 0; i < 4; ++i) {
    int c = i * 256 + lane * 4;
    float4 gg = *(const float4*)(g + c);
    float4 bb = *(const float4*)(b + c);
    unsigned short o[4];
    o[0] = f2bf((x[i].x - mu) * rs * gg.x + bb.x);
    o[1] = f2bf((x[i].y - mu) * rs * gg.y + bb.y);
    o[2] = f2bf((x[i].z - mu) * rs * gg.z + bb.z);
    o[3] = f2bf((x[i].w - mu) * rs * gg.w + bb.w);
    *(ushort4*)(xq + (size_t)row * C_ + c) = *(ushort4*)o;
  }
}

// ---------------- K -> bf16, pre-swizzled into MFMA B-fragment order --------
// kq[((sc2*8+kc)*2+sn)*64+lane][j] = K[s][d],
//   s = sc2*32 + sn*16 + (lane&15), d = kc*32 + (lane>>4)*8 + j
__global__ __launch_bounds__(256) void prep_k(const float* __restrict__ wfc,
                                              unsigned short* __restrict__ kq) {
  int t = blockIdx.x * 256 + threadIdx.x;
  int lane = t & 63;
  int sn  = (t >> 6) & 1;
  int kc  = (t >> 7) & 7;
  int sc2 = t >> 10;
  int s = sc2 * 32 + sn * 16 + (lane & 15);
  int d = kc * 32 + (lane >> 4) * 8;
  const float* src = wfc + (size_t)s * D_ + d;
  float4 a = *(const float4*)src;
  float4 b = *(const float4*)(src + 4);
  unsigned short o[8] = { f2bf(a.x), f2bf(a.y), f2bf(a.z), f2bf(a.w),
                          f2bf(b.x), f2bf(b.y), f2bf(b.z), f2bf(b.w) };
  *(uint4*)(kq + (size_t)t * 8) = *(uint4*)o;
}

// ---------------- V -> bf16, pre-swizzled into MFMA B-fragment order --------
// vq[((sc2*16+dn)*64+lane)*8+j] = V[s][d],
//   s = sc2*32 + (lane>>4)*8 + j, d = dn*16 + (lane&15)
//   V[s][d] = w_proj[(s&3)*256 + d][s>>2]
__global__ __launch_bounds__(256) void prep_v(const float* __restrict__ wproj,
                                              unsigned short* __restrict__ vq) {
  __shared__ unsigned short tile[8192];   // [p=(s&3)*256+d][c=(s_local>>2)] : 1024 x 8
  int b = blockIdx.x;
  int tid = threadIdx.x;
  int c0 = b * 8;
  #pragma unroll
  for (int it = 0; it < 4; ++it) {
    int row = it * 256 + tid;
    const float* src = wproj + (size_t)row * C_ + c0;
    float4 a = *(const float4*)src;
    float4 bb = *(const float4*)(src + 4);
    unsigned short* dst = &tile[row * 8];
    dst[0] = f2bf(a.x);  dst[1] = f2bf(a.y);  dst[2] = f2bf(a.z);  dst[3] = f2bf(a.w);
    dst[4] = f2bf(bb.x); dst[5] = f2bf(bb.y); dst[6] = f2bf(bb.z); dst[7] = f2bf(bb.w);
  }
  __syncthreads();
  #pragma unroll
  for (int it = 0; it < 4; ++it) {
    int slot = it * 256 + tid;
    int lane = slot & 63;
    int dn   = slot >> 6;
    int d = dn * 16 + (lane & 15);
    int sl0 = (lane >> 4) * 8;
    unsigned short o[8];
    #pragma unroll
    for (int j = 0; j < 8; ++j) {
      int sl = sl0 + j;
      o[j] = tile[((sl & 3) * 256 + d) * 8 + (sl >> 2)];
    }
    *(uint4*)(vq + (size_t)b * 8192 + (size_t)slot * 8) = *(uint4*)o;
  }
}

// ---------------- fused main: 8 waves, scores 4Mx2S, PV 4Nx2M ---------------
__global__ __launch_bounds__(512, 2) void mlpmha_main(
    const unsigned short* __restrict__ xq,
    const unsigned short* __restrict__ kq,
    const unsigned short* __restrict__ vq,
    const float* __restrict__ res,
    float* __restrict__ out) {
  __shared__ unsigned short ldsK[2][8192];   // 16KB x2, fragment-linear
  __shared__ unsigned short ldsV[8192];      // 16KB, fragment-linear
  __shared__ unsigned short ldsP[128][36];   // +4 pad

  int tid  = threadIdx.x;
  int wave = tid >> 6;
  int lane = tid & 63;
  int l16  = lane & 15;
  int quad = lane >> 4;
  int wgM  = blockIdx.x * 128;

  // scores assignment: wave = (mi, si) -> 32 rows, 16 s-cols
  int mi = wave & 3, si = wave >> 2;
  // PV assignment: wave = (ni, mi2) -> 64 cols, 64 rows
  int ni = wave & 3, mi2 = wave >> 2;

  // Q fragments: 2 m-tiles x 8 k-chunks, register resident
  bf16x8 qf[2][8];
  #pragma unroll
  for (int mt = 0; mt < 2; ++mt) {
    const unsigned short* qr =
        xq + (size_t)(wgM + mi * 32 + mt * 16 + l16) * D_ + quad * 8;
    #pragma unroll
    for (int kc = 0; kc < 8; ++kc) qf[mt][kc] = *(const bf16x8*)(qr + kc * 32);
  }

  f32x4 acc[4][4];   // [mt2][dnl]
  #pragma unroll
  for (int i = 0; i < 4; ++i)
    #pragma unroll
    for (int j = 0; j < 4; ++j) acc[i][j] = (f32x4){0.f, 0.f, 0.f, 0.f};

  int soff = tid * 8;   // staging offset (shorts): wave-uniform base + lane*16B

  // prologue: K chunk 0 -> buf 0
  {
    const unsigned short* kg = kq + soff;
    async16(kg, &ldsK[0][soff]);
    async16(kg + 4096, &ldsK[0][soff + 4096]);
  }
  __syncthreads();

  for (int sc = 0; sc < NCH; ++sc) {
    int cur = sc & 1;

    // prefetch V(sc) during scores
    {
      const unsigned short* vg = vq + (size_t)sc * 8192 + soff;
      async16(vg, &ldsV[soff]);
      async16(vg + 4096, &ldsV[soff + 4096]);
    }

    // ---- scores: 32 rows x 16 s-cols per wave, K=256
    f32x4 sacc[2];
    sacc[0] = (f32x4){0.f, 0.f, 0.f, 0.f};
    sacc[1] = (f32x4){0.f, 0.f, 0.f, 0.f};
    #pragma unroll
    for (int kc = 0; kc < 8; ++kc) {
      bf16x8 kb = *(const bf16x8*)&ldsK[cur][(kc * 2 + si) * 512 + lane * 8];
      #pragma unroll
      for (int mt = 0; mt < 2; ++mt)
        sacc[mt] = __builtin_amdgcn_mfma_f32_16x16x32_bf16(qf[mt][kc], kb, sacc[mt], 0, 0, 0);
    }

    // ---- P = relu(score)^2 -> shared LDS
    #pragma unroll
    for (int mt = 0; mt < 2; ++mt)
      #pragma unroll
      for (int r = 0; r < 4; ++r) {
        float v = sacc[mt][r];
        v = v > 0.f ? v * v : 0.f;
        ldsP[mi * 32 + mt * 16 + quad * 4 + r][si * 16 + l16] = f2bf(v);
      }

    __syncthreads();   // P visible; V(sc) drained

    // prefetch K(sc+1) during PV
    if (sc + 1 < NCH) {
      const unsigned short* kg = kq + (size_t)(sc + 1) * 8192 + soff;
      async16(kg, &ldsK[1 - cur][soff]);
      async16(kg + 4096, &ldsK[1 - cur][soff + 4096]);
    }

    // ---- PV: 64 rows x 64 cols per wave, K = 32
    {
      bf16x8 vb[4];
      #pragma unroll
      for (int dnl = 0; dnl < 4; ++dnl)
        vb[dnl] = *(const bf16x8*)&ldsV[((ni * 4 + dnl) * 64 + lane) * 8];
      #pragma unroll
      for (int mt2 = 0; mt2 < 4; ++mt2) {
        const unsigned short* pp = &ldsP[mi2 * 64 + mt2 * 16 + l16][quad * 8];
        union { ushort4 h[2]; bf16x8 v; } pu;
        pu.h[0] = *(const ushort4*)pp;
        pu.h[1] = *(const ushort4*)(pp + 4);
        bf16x8 pa = pu.v;
        #pragma unroll
        for (int dnl = 0; dnl < 4; ++dnl)
          acc[mt2][dnl] = __builtin_amdgcn_mfma_f32_16x16x32_bf16(pa, vb[dnl], acc[mt2][dnl], 0, 0, 0);
      }
    }

    __syncthreads();   // P/V reusable; K(sc+1) drained
  }

  // ---- epilogue: out = residual + acc
  #pragma unroll
  for (int mt2 = 0; mt2 < 4; ++mt2)
    #pragma unroll
    for (int r = 0; r < 4; ++r) {
      size_t row = (size_t)(wgM + mi2 * 64 + mt2 * 16 + quad * 4 + r) * D_;
      #pragma unroll
      for (int dnl = 0; dnl < 4; ++dnl) {
        size_t idx = row + ni * 64 + dnl * 16 + l16;
        out[idx] = res[idx] + acc[mt2][dnl][r];
      }
    }
}

extern "C" void kernel_launch(void* const* d_in, const int* in_sizes, int n_in,
                              void* d_out, int out_size, void* d_ws, size_t ws_size,
                              hipStream_t stream) {
  const float* res   = (const float*)d_in[0];
  const float* wfc   = (const float*)d_in[1];
  const float* wproj = (const float*)d_in[2];
  const float* g     = (const float*)d_in[3];
  const float* b     = (const float*)d_in[4];
  float* out = (float*)d_out;

  unsigned short* xq = (unsigned short*)d_ws;              // 32768*256 bf16 = 16 MB
  unsigned short* kq = xq + (size_t)MROWS * D_;            // 4096*256 bf16  =  2 MB
  unsigned short* vq = kq + (size_t)S_TOT * D_;            // 4096*256 bf16  =  2 MB

  ln_kernel<<<2048, 256, 0, stream>>>(res, g, b, xq);
  prep_k<<<512, 256, 0, stream>>>(wfc, kq);
  prep_v<<<128, 256, 0, stream>>>(wproj, vq);
  mlpmha_main<<<256, 512, 0, stream>>>(xq, kq, vq, res, out);
}